// Round 17
// baseline (102.742 us; speedup 1.0000x reference)
//
#include <hip/hip_runtime.h>
#include <hip/hip_bf16.h>
#include <math.h>

// Problem constants (B=2, S=1024, DM=1024, QH=16, KVH=4)
constexpr int B_   = 2;
constexpr int S_   = 1024;
constexpr int DM_  = 1024;
constexpr int QH_  = 16;
constexpr int KVH_ = 4;
constexpr int DH_  = 64;
constexpr int DHH_ = 32;
constexpr int M_   = 32;    // sqrt(S)
constexpr int TOPK_ = 8;
constexpr int BS_  = B_ * S_;                    // 2048
constexpr int NW_  = QH_*DH_ + 2*KVH_*DH_;       // 1536 (q|k|v fused row)
constexpr int KOFF_ = QH_*DH_;                   // 1024
constexpr int VOFF_ = KOFF_ + KVH_*DH_;          // 1280

typedef __attribute__((ext_vector_type(8))) short short8v;   // 8 bf16 (4 VGPR)
typedef __attribute__((ext_vector_type(4))) short short4v;   // 4 bf16 (8B)
typedef __attribute__((ext_vector_type(4))) float float4v;   // MFMA acc

__device__ inline unsigned short bf16_rne(float f) {
    unsigned u = __float_as_uint(f);
    return (unsigned short)((u + 0x7FFFu + ((u >> 16) & 1u)) >> 16);
}
__device__ inline float bf16_back(unsigned short h) {
    return __uint_as_float(((unsigned)h) << 16);
}
__device__ __forceinline__ int swz(int srow) { return ((srow >> 1) & 3) << 4; }

// global -> LDS async copy, 16 B per lane at (ldsbase + lane*16).
__device__ __forceinline__ void gl_lds16(const void* g, void* l) {
    auto* gp = reinterpret_cast<const __attribute__((address_space(1))) unsigned int*>(
        reinterpret_cast<uintptr_t>(g));
    auto* lp = reinterpret_cast<__attribute__((address_space(3))) unsigned int*>(
        reinterpret_cast<uintptr_t>(l));
    __builtin_amdgcn_global_load_lds(gp, lp, 16, 0, 0);
}

// ---------------------------------------------------------------------------
// Sortable f64 keys (round-13 verified).
// ---------------------------------------------------------------------------
__device__ __forceinline__ unsigned sortable(float v) {
    unsigned u = __float_as_uint(v);
    return u ^ ((unsigned)(((int)u) >> 31) | 0x80000000u);
}
__device__ __forceinline__ float unsortable(unsigned s) {
    return __uint_as_float(s ^ (~((unsigned)(((int)s) >> 31)) | 0x80000000u));
}
__device__ __forceinline__ double mkkey(float v, int idx) {
    return (double)sortable(v) * 64.0 + (double)(63 - idx);
}
__device__ __forceinline__ void unkey(double kd, float& v, int& idx) {
    double t = trunc(kd * 0.015625);
    idx = 63 - (int)(kd - t * 64.0);
    v = unsortable((unsigned)t);
}
__device__ __forceinline__ double mkkey2(float v, int c, int row, int col) {
    return (double)sortable(v) * 65536.0 +
           (double)(65535 - (c * 1024 + row * 32 + col));
}
__device__ __forceinline__ void unkey2(double kd, float& v, int& vrow) {
    double t = trunc(kd * (1.0 / 65536.0));
    int low = 65535 - (int)(kd - t * 65536.0);
    v = unsortable((unsigned)t);
    vrow = ((low >> 5) & 31) * 32 + (low & 31);   // row*32 + col
}
__device__ __forceinline__ void ins8(double* l, double x) {
    l[7] = fmax(fmin(l[6], x), l[7]);
    l[6] = fmax(fmin(l[5], x), l[6]);
    l[5] = fmax(fmin(l[4], x), l[5]);
    l[4] = fmax(fmin(l[3], x), l[4]);
    l[3] = fmax(fmin(l[2], x), l[3]);
    l[2] = fmax(fmin(l[1], x), l[2]);
    l[1] = fmax(fmin(l[0], x), l[1]);
    l[0] = fmax(x, l[0]);
}

// ---------------------------------------------------------------------------
// Banded "LDS image" split planes (round-11 verified).
// ---------------------------------------------------------------------------
template<int L>
__device__ __forceinline__ void split_banded(const float* __restrict__ src,
                                             int i, char* __restrict__ dst,
                                             int row0)
{
    float4 v = reinterpret_cast<const float4*>(src)[i];
    int row = row0 + (i >> 8);
    int col = (i & 255) << 2;
    int srow = row & 63;
    char* band = dst + (size_t)(row >> 6) * (32u * L * 4096u);
    int off = ((col >> 5) * L) * 4096 + srow * 64 +
              ((((col & 31) >> 3) * 16) ^ swz(srow)) + (col & 7) * 2;
    float f[4] = {v.x, v.y, v.z, v.w};
#pragma unroll
    for (int l = 0; l < L; ++l) {
        short4v s;
#pragma unroll
        for (int e = 0; e < 4; ++e) {
            unsigned short h = bf16_rne(f[e]);
            s[e] = (short)h;
            f[e] -= bf16_back(h);
        }
        *reinterpret_cast<short4v*>(band + off + l * 4096) = s;
    }
}

__global__ __launch_bounds__(256) void split_all_kernel(
    const float* __restrict__ x,  const float* __restrict__ wq,
    const float* __restrict__ wk, const float* __restrict__ wv,
    const float* __restrict__ wo,
    char* __restrict__ xs, char* __restrict__ wsp, char* __restrict__ wob)
{
    constexpr int E0 = BS_ * DM_ / 4;
    constexpr int E1 = E0 + KOFF_ * DM_ / 4;
    constexpr int E2 = E1 + (VOFF_ - KOFF_) * DM_ / 4;
    constexpr int E3 = E2 + (NW_ - VOFF_) * DM_ / 4;
    constexpr int E4 = E3 + DM_ * DM_ / 4;
    int i = blockIdx.x * 256 + threadIdx.x;
    if (i < E0)      split_banded<3>(x,  i,      xs,  0);
    else if (i < E1) split_banded<3>(wq, i - E0, wsp, 0);
    else if (i < E2) split_banded<3>(wk, i - E1, wsp, KOFF_);
    else if (i < E3) split_banded<3>(wv, i - E2, wsp, VOFF_);
    else if (i < E4) split_banded<1>(wo, i - E3, wob, 0);
}

// ---------------------------------------------------------------------------
// global_load_lds MFMA GEMM, 64x64 tile (round-13/16 proven structure).
// ---------------------------------------------------------------------------
template<int LEVELS, int CROSS>
__global__ __launch_bounds__(256) void gemm_glds_kernel(
    const char* __restrict__ Aimg, const char* __restrict__ Bimg,
    int nVstart, float* __restrict__ C, int N, int K)
{
    __shared__ char As[2][LEVELS * 4096];
    __shared__ char Bs[2][LEVELS * 4096];
    const int tid = threadIdx.x;
    const int rowBase = blockIdx.x * 64;
    const int colBase = blockIdx.y * 64;
    const int lane = tid & 63, wvi = tid >> 6;
    const int wr = wvi >> 1, wc = wvi & 1;
    const int fr = lane & 15, fk = lane >> 4;
    const int LA = (colBase >= nVstart) ? 1 : LEVELS;

    const char* Ab = Aimg + (size_t)blockIdx.x * (32u * LEVELS * 4096u);
    const char* Bb = Bimg + (size_t)blockIdx.y * (32u * LEVELS * 4096u);

    float4v acc[2][2];
#pragma unroll
    for (int mi = 0; mi < 2; ++mi)
#pragma unroll
        for (int ni = 0; ni < 2; ++ni) acc[mi][ni] = (float4v)0.f;

    const int NKC = K >> 5;
    auto stage = [&](int kc, int buf) {
        const int kb = kc * LEVELS * 4096;
        const int toff = wvi * 1024 + lane * 16;
#pragma unroll
        for (int l = 0; l < LEVELS; ++l) if (l < LA) {
            gl_lds16(Ab + kb + l * 4096 + toff, &As[buf][l * 4096 + toff]);
            gl_lds16(Bb + kb + l * 4096 + toff, &Bs[buf][l * 4096 + toff]);
        }
    };

    stage(0, 0);
    __syncthreads();
    int buf = 0;
    for (int kc = 0; kc < NKC; ++kc) {
        if (kc + 1 < NKC) stage(kc + 1, buf ^ 1);
        short8v aF[LEVELS][2];
#pragma unroll
        for (int l = 0; l < LEVELS; ++l) if (l < LA)
#pragma unroll
            for (int mi = 0; mi < 2; ++mi) {
                int row = wr * 32 + mi * 16 + fr;
                aF[l][mi] = *reinterpret_cast<const short8v*>(
                    &As[buf][l * 4096 + row * 64 + ((fk * 16) ^ swz(row))]);
            }
#pragma unroll
        for (int lb = 0; lb < LEVELS; ++lb) {
            if (lb >= LA) continue;
            short8v bF[2];
#pragma unroll
            for (int ni = 0; ni < 2; ++ni) {
                int row = wc * 32 + ni * 16 + fr;
                bF[ni] = *reinterpret_cast<const short8v*>(
                    &Bs[buf][lb * 4096 + row * 64 + ((fk * 16) ^ swz(row))]);
            }
#pragma unroll
            for (int la = 0; la < LEVELS; ++la) {
                if (la >= LA || la + lb > CROSS) continue;
#pragma unroll
                for (int mi = 0; mi < 2; ++mi)
#pragma unroll
                    for (int ni = 0; ni < 2; ++ni)
                        acc[mi][ni] = __builtin_amdgcn_mfma_f32_16x16x32_bf16(
                            aF[la][mi], bF[ni], acc[mi][ni], 0, 0, 0);
            }
        }
        __syncthreads();
        buf ^= 1;
    }
#pragma unroll
    for (int mi = 0; mi < 2; ++mi)
#pragma unroll
        for (int ni = 0; ni < 2; ++ni) {
            int row0 = rowBase + wr * 32 + mi * 16 + fk * 4;
            int col  = colBase + wc * 32 + ni * 16 + fr;
#pragma unroll
            for (int j = 0; j < 4; ++j)
                C[(size_t)(row0 + j) * N + col] = acc[mi][ni][j];
        }
}

// ---------------------------------------------------------------------------
// Round-8 in-kernel-split GEMM — FALLBACK when ws_size too small.
// ---------------------------------------------------------------------------
template<int LEVELS, int CROSS>
__global__ __launch_bounds__(256) void gemm_mfma_kernel(
    const float* __restrict__ A,
    const float* __restrict__ W0, const float* __restrict__ W1,
    const float* __restrict__ W2, int n1, int n2,
    float* __restrict__ C, int N, int K)
{
    __shared__ short As[LEVELS * 64 * 32];
    __shared__ short Bs[LEVELS * 64 * 32];
    const int tid = threadIdx.x;
    const int rowBase = blockIdx.x * 64;
    const int colBase = blockIdx.y * 64;
    const int lane = tid & 63, wvi = tid >> 6;
    const int wr = wvi >> 1, wc = wvi & 1;
    const int fr = lane & 15, fk = lane >> 4;

    const float* aptr[2]; const float* bptr[2];
    int arow_[2], ac4_[2];
#pragma unroll
    for (int i = 0; i < 2; ++i) {
        int q = i * 256 + tid;
        int row = q >> 3, c4 = q & 7;
        arow_[i] = row; ac4_[i] = c4;
        aptr[i] = A + (size_t)(rowBase + row) * K + c4 * 4;
        int n = colBase + row;
        const float* wrow = (n < n1) ? W0 + (size_t)n * K
                          : (n < n2) ? W1 + (size_t)(n - n1) * K
                                     : W2 + (size_t)(n - n2) * K;
        bptr[i] = wrow + c4 * 4;
    }
    float4 pa[2], pb[2];
#pragma unroll
    for (int i = 0; i < 2; ++i) {
        pa[i] = *reinterpret_cast<const float4*>(aptr[i]);
        pb[i] = *reinterpret_cast<const float4*>(bptr[i]);
    }
    float4v acc[2][2];
#pragma unroll
    for (int mi = 0; mi < 2; ++mi)
#pragma unroll
        for (int ni = 0; ni < 2; ++ni) acc[mi][ni] = (float4v)0.f;

    const int NKC = K >> 5;
    for (int kc = 0; kc < NKC; ++kc) {
#pragma unroll
        for (int i = 0; i < 2; ++i) {
            int row = arow_[i];
            int base = row * 64 + ((ac4_[i] * 8) ^ swz(row));
            float fa[4] = {pa[i].x, pa[i].y, pa[i].z, pa[i].w};
            float fb[4] = {pb[i].x, pb[i].y, pb[i].z, pb[i].w};
#pragma unroll
            for (int l = 0; l < LEVELS; ++l) {
                short4v sa, sb;
#pragma unroll
                for (int e = 0; e < 4; ++e) {
                    unsigned short ha = bf16_rne(fa[e]);
                    unsigned short hb = bf16_rne(fb[e]);
                    sa[e] = (short)ha; sb[e] = (short)hb;
                    fa[e] -= bf16_back(ha);
                    fb[e] -= bf16_back(hb);
                }
                *reinterpret_cast<short4v*>((char*)As + l * 4096 + base) = sa;
                *reinterpret_cast<short4v*>((char*)Bs + l * 4096 + base) = sb;
            }
        }
        __syncthreads();
        if (kc + 1 < NKC) {
#pragma unroll
            for (int i = 0; i < 2; ++i) {
                pa[i] = *reinterpret_cast<const float4*>(aptr[i] + (kc+1)*32);
                pb[i] = *reinterpret_cast<const float4*>(bptr[i] + (kc+1)*32);
            }
        }
        short8v aF[LEVELS][2];
#pragma unroll
        for (int l = 0; l < LEVELS; ++l)
#pragma unroll
            for (int mi = 0; mi < 2; ++mi) {
                int row = wr * 32 + mi * 16 + fr;
                aF[l][mi] = *reinterpret_cast<const short8v*>(
                    (const char*)As + l * 4096 + row * 64 + ((fk * 16) ^ swz(row)));
            }
#pragma unroll
        for (int lb = 0; lb < LEVELS; ++lb) {
            short8v bF[2];
#pragma unroll
            for (int ni = 0; ni < 2; ++ni) {
                int row = wc * 32 + ni * 16 + fr;
                bF[ni] = *reinterpret_cast<const short8v*>(
                    (const char*)Bs + lb * 4096 + row * 64 + ((fk * 16) ^ swz(row)));
            }
#pragma unroll
            for (int la = 0; la < LEVELS; ++la) {
                if (la + lb > CROSS) continue;
#pragma unroll
                for (int mi = 0; mi < 2; ++mi)
#pragma unroll
                    for (int ni = 0; ni < 2; ++ni)
                        acc[mi][ni] = __builtin_amdgcn_mfma_f32_16x16x32_bf16(
                            aF[la][mi], bF[ni], acc[mi][ni], 0, 0, 0);
            }
        }
        __syncthreads();
    }
#pragma unroll
    for (int mi = 0; mi < 2; ++mi)
#pragma unroll
        for (int ni = 0; ni < 2; ++ni) {
            int row0 = rowBase + wr * 32 + mi * 16 + fk * 4;
            int col  = colBase + wc * 32 + ni * 16 + fr;
#pragma unroll
            for (int j = 0; j < 4; ++j)
                C[(size_t)(row0 + j) * N + col] = acc[mi][ni][j];
        }
}

// ---------------------------------------------------------------------------
// Trig table gen (round-16 verified): 32768 (s,d) pairs, bit-identical
// recipe (f64 pow -> f32 div -> f32 angle -> f64 sincos -> f32).
// ---------------------------------------------------------------------------
__global__ __launch_bounds__(256) void tabgen_kernel(float2* __restrict__ tab)
{
    int i = blockIdx.x * 256 + threadIdx.x;    // 32768
    int d = i & 31, s = i >> 5;
    double e = (double)d * (1.0 / 32.0);
    float pf = (float)pow(10000.0, e);         // correctly-rounded powf
    float inv_freq = __fdiv_rn(1.0f, pf);      // numpy's 2nd f32 rounding
    float ang = __fmul_rn((float)s, inv_freq);
    double sn64, cs64;
    sincos((double)ang, &sn64, &cs64);
    tab[i] = make_float2((float)cs64, (float)sn64);
}

// self-contained in-place rope (FALLBACK path only).
__global__ __launch_bounds__(256) void rope_kernel(float* __restrict__ qkv)
{
    int id = blockIdx.x * 256 + threadIdx.x;
    int d  = id & 31;
    int r  = id >> 5;
    int h  = r % (QH_ + KVH_);
    int bs = r / (QH_ + KVH_);
    int s  = bs & (S_ - 1);
    float* base = qkv + (size_t)bs * NW_ +
                  (h < QH_ ? h * DH_ : KOFF_ + (h - QH_) * DH_);
    double e = (double)d * (1.0 / 32.0);
    float pf = (float)pow(10000.0, e);
    float inv_freq = __fdiv_rn(1.0f, pf);
    float ang = __fmul_rn((float)s, inv_freq);
    double sn64, cs64;
    sincos((double)ang, &sn64, &cs64);
    float cs = (float)cs64;
    float sn = (float)sn64;
    float x1 = base[d];
    float x2 = base[d + DHH_];
    base[d]        = __fadd_rn(__fmul_rn(x1, cs), __fmul_rn(-x2, sn));
    base[d + DHH_] = __fadd_rn(__fmul_rn(x2, cs), __fmul_rn(x1, sn));
}

// ---------------------------------------------------------------------------
// k1/k2 grid sums, ROPE folded in (rotation is a pure intermediate: rotated
// k is consumed ONLY here, so rotate-on-read deletes the standalone rope
// pass).  Rotation uses the same tab values + same strict-f32 mul/add
// sequence as rope_kernel -> summands bit-identical; f64 mc-ascending sum
// order unchanged -> k1/k2 bit-identical to round 16.
// 256 blocks x 64 threads (round-16 verified shape).
// ---------------------------------------------------------------------------
template<bool ROPE>
__global__ __launch_bounds__(64) void k1k2_kernel(
    const float* __restrict__ qkv, const float2* __restrict__ tab,
    float* __restrict__ k1, float* __restrict__ k2)
{
    int blk = blockIdx.x;            // (b*KVH+kv)*32 + m : 256 blocks
    int m   = blk & 31;
    int bkv = blk >> 5;
    int b = bkv >> 2, kv = bkv & 3;
    int tid = threadIdx.x;
    int d = tid & 31;
    bool hi = tid >= 32;
    const float* kbase = qkv + (size_t)b * S_ * NW_ + KOFF_ + kv * DH_;
    double s = 0.;
    if (!hi) {
        for (int mc = 0; mc < M_; ++mc) {
            int r = m * M_ + mc;                 // == sequence index s
            const float* kr = kbase + (size_t)r * NW_;
            float e;
            if (ROPE) {
                float2 t = tab[(r << 5) | d];
                e = __fadd_rn(__fmul_rn(kr[d], t.x),
                              __fmul_rn(-kr[d + DHH_], t.y));
            } else e = kr[d];
            s += (double)e;
        }
        k1[((b * KVH_ + kv) * M_ + m) * DHH_ + d] = (float)s;
    } else {
        for (int mc = 0; mc < M_; ++mc) {
            int r = mc * M_ + m;
            const float* kr = kbase + (size_t)r * NW_;
            float e;
            if (ROPE) {
                float2 t = tab[(r << 5) | d];
                e = __fadd_rn(__fmul_rn(kr[d + DHH_], t.x),
                              __fmul_rn(kr[d], t.y));
            } else e = kr[d + DHH_];
            s += (double)e;
        }
        k2[((b * KVH_ + kv) * M_ + m) * DHH_ + d] = (float)s;
    }
}

// ---------------------------------------------------------------------------
// selS: lane-per-problem selection (round-13 verified), ROPE folded in:
// q row loaded raw, rotated in registers with the block's tab slice staged
// to LDS (coalesced) -- values and subsequent fmaf dot order bit-identical
// to round 16.  (64,1) bounds -> ~120 live VGPR, far under 512: no spill.
// ---------------------------------------------------------------------------
template<bool ROPE>
__global__ __launch_bounds__(64, 1) void selS_kernel(
    const float* __restrict__ qkv, const float2* __restrict__ tab,
    const float* __restrict__ k1g, const float* __restrict__ k2g,
    float* __restrict__ meta)
{
    __shared__ __align__(16) float k1s[M_][DHH_];
    __shared__ __align__(16) float k2s[M_][DHH_];
    __shared__ float2 qt[64][DHH_];    // this block's 64 s-rows of trig
    const int lane = threadIdx.x;
    const int bh   = blockIdx.x >> 4;
    const int sblk = blockIdx.x & 15;
    const int b    = bh >> 4;
    const int h    = bh & 15;
    const int kv   = h >> 2;
    const int s    = sblk * 64 + lane;

    const int kbase = (b * KVH_ + kv) * M_ * DHH_;
    for (int i = lane; i < M_ * DHH_; i += 64) {
        k1s[i >> 5][i & 31] = k1g[kbase + i];
        k2s[i >> 5][i & 31] = k2g[kbase + i];
    }
    if (ROPE) {
        const float2* tb = tab + (size_t)(sblk * 64) * DHH_;
        for (int i = lane; i < 64 * DHH_; i += 64)
            qt[i >> 5][i & 31] = tb[i];            // coalesced
    }
    __syncthreads();

    const float* qrow = qkv + (size_t)(b * S_ + s) * NW_ + h * DH_;

    // ---- load full q row, rotate in registers (bit-identical to rope)
    float q[64];
#pragma unroll
    for (int i = 0; i < 16; ++i)
        *reinterpret_cast<float4*>(&q[i * 4]) =
            *reinterpret_cast<const float4*>(qrow + i * 4);
    if (ROPE) {
#pragma unroll
        for (int d = 0; d < DHH_; ++d) {
            float2 t = qt[lane][d];
            float x1 = q[d], x2 = q[d + DHH_];
            q[d]        = __fadd_rn(__fmul_rn(x1, t.x), __fmul_rn(-x2, t.y));
            q[d + DHH_] = __fadd_rn(__fmul_rn(x2, t.x), __fmul_rn(x1, t.y));
        }
    }

    // ---- stage-1 s1: q[0:32] . k1[m]  (same fmaf chain as rounds 13-16)
    double l1[8];
#pragma unroll
    for (int p = 0; p < 8; ++p) l1[p] = -1.0;
    for (int m = 0; m < M_; ++m) {
        float acc = 0.f;
#pragma unroll
        for (int d4 = 0; d4 < 8; ++d4) {
            float4 k4 = *reinterpret_cast<const float4*>(&k1s[m][d4 * 4]);
            acc = fmaf(q[d4 * 4 + 0], k4.x, acc);
            acc = fmaf(q[d4 * 4 + 1], k4.y, acc);
            acc = fmaf(q[d4 * 4 + 2], k4.z, acc);
            acc = fmaf(q[d4 * 4 + 3], k4.w, acc);
        }
        ins8(l1, mkkey(acc, m));
    }
    // ---- stage-1 s2: q[32:64] . k2[m]
    double l2[8];
#pragma unroll
    for (int p = 0; p < 8; ++p) l2[p] = -1.0;
    for (int m = 0; m < M_; ++m) {
        float acc = 0.f;
#pragma unroll
        for (int d4 = 0; d4 < 8; ++d4) {
            float4 k4 = *reinterpret_cast<const float4*>(&k2s[m][d4 * 4]);
            acc = fmaf(q[32 + d4 * 4 + 0], k4.x, acc);
            acc = fmaf(q[32 + d4 * 4 + 1], k4.y, acc);
            acc = fmaf(q[32 + d4 * 4 + 2], k4.z, acc);
            acc = fmaf(q[32 + d4 * 4 + 3], k4.w, acc);
        }
        ins8(l2, mkkey(acc, m));
    }
    float av[8], bv[8]; int i1v[8], i2v[8];
#pragma unroll
    for (int p = 0; p < 8; ++p) { unkey(l1[p], av[p], i1v[p]);
                                  unkey(l2[p], bv[p], i2v[p]); }

    // ---- stage-2: frontier (i+1)(j+1)<=8, keys carry (c,row,col)
    double l[8];
#pragma unroll
    for (int p = 0; p < 8; ++p) l[p] = -1.0;
#define CAND(i, j) ins8(l, mkkey2(av[i] + bv[j], (i)*8+(j), i1v[i], i2v[j]))
    CAND(0,0); CAND(0,1); CAND(0,2); CAND(0,3);
    CAND(0,4); CAND(0,5); CAND(0,6); CAND(0,7);
    CAND(1,0); CAND(1,1); CAND(1,2); CAND(1,3);
    CAND(2,0); CAND(2,1); CAND(3,0); CAND(3,1);
    CAND(4,0); CAND(5,0); CAND(6,0); CAND(7,0);
#undef CAND
    float v2[8]; int vrow[8];
#pragma unroll
    for (int p = 0; p < 8; ++p) unkey2(l[p], v2[p], vrow[p]);

    float ex[8]; float sum = 0.f;
#pragma unroll
    for (int t = 0; t < 8; ++t) { ex[t] = expf((v2[t] - v2[0]) * 0.125f);
                                  sum += ex[t]; }
    const float inv = 1.0f / sum;

    float* mp = meta + ((size_t)(bh * S_ + s)) * 16;
#pragma unroll
    for (int t = 0; t < 8; ++t) {
        mp[t]     = ex[t] * inv;
        mp[8 + t] = __int_as_float(vrow[t]);
    }
}

// ---------------------------------------------------------------------------
// gatherV: one wave per problem, coalesced v-row gather (round-13 verified).
// ---------------------------------------------------------------------------
template<int OUTMODE>
__global__ __launch_bounds__(256) void gatherV_kernel(
    const float* __restrict__ qkv, const float* __restrict__ meta,
    void* __restrict__ aout)
{
    const int tid  = threadIdx.x;
    const int w    = tid >> 6, lane = tid & 63;
    const int pid  = blockIdx.x * 4 + w;       // (bh*S + s)
    const int bh   = pid >> 10;
    const int s    = pid & 1023;
    const int b    = bh >> 4;
    const int h    = bh & 15;
    const int kv   = h >> 2;

    const float* mp = meta + (size_t)pid * 16;
    float mv = (lane < 16) ? mp[lane] : 0.f;

    const float* vbase = qkv + (size_t)b * S_ * NW_ + VOFF_ + kv * DH_ + lane;
    float o = 0.f;
#pragma unroll
    for (int t = 0; t < 8; ++t) {
        float wt = __shfl(mv, t);
        int   vr = __float_as_int(__shfl(mv, 8 + t));
        o = fmaf(wt, vbase[(size_t)vr * NW_], o);
    }
    int orow = b * S_ + s;
    int ocol = h * DH_ + lane;
    if (OUTMODE == 1) {
        int srow = orow & 63;
        size_t byteoff = (size_t)(orow >> 6) * (32u * 4096u)
                       + (size_t)(ocol >> 5) * 4096 + srow * 64
                       + ((((ocol & 31) >> 3) * 16) ^ swz(srow))
                       + (ocol & 7) * 2;
        *reinterpret_cast<short*>((char*)aout + byteoff) = (short)bf16_rne(o);
    } else {
        ((float*)aout)[(size_t)orow * (QH_ * DH_) + ocol] = o;
    }
}

// ---------------------------------------------------------------------------
extern "C" void kernel_launch(void* const* d_in, const int* in_sizes, int n_in,
                              void* d_out, int out_size, void* d_ws,
                              size_t ws_size, hipStream_t stream)
{
    const float* x  = (const float*)d_in[0];
    const float* wq = (const float*)d_in[1];
    const float* wk = (const float*)d_in[2];
    const float* wv = (const float*)d_in[3];
    const float* wo = (const float*)d_in[4];
    float* out = (float*)d_out;

    float* wsf = (float*)d_ws;
    float* qkv = wsf;                                    // 2048*1536 f32
    float* k1  = qkv + (size_t)BS_ * NW_;                // 8192 f32
    float* k2  = k1 + B_ * KVH_ * M_ * DHH_;             // 8192 f32

    const bool fast = ws_size >= 40960000ull;

    if (fast) {
        char* xs  = (char*)(k2 + B_ * KVH_ * M_ * DHH_);
        char* wsp = xs  + (size_t)3 * BS_ * DM_ * 2;
        char* wob = wsp + (size_t)3 * NW_ * DM_ * 2;
        char* aob = wob + (size_t)DM_ * DM_ * 2;
        float*  meta = (float*)xs;              // xs dead after qkv GEMM (2MB)
        float2* tab  = (float2*)(xs + (4u << 20));  // +4MB: 256KB trig table

        constexpr int NSLOT = (BS_*DM_ + KOFF_*DM_ + (VOFF_-KOFF_)*DM_ +
                               (NW_-VOFF_)*DM_ + DM_*DM_) / 4;
        split_all_kernel<<<(NSLOT + 255) / 256, 256, 0, stream>>>(
            x, wq, wk, wv, wo, xs, wsp, wob);

        dim3 g1(BS_ / 64, NW_ / 64);
        gemm_glds_kernel<3, 2><<<g1, 256, 0, stream>>>(
            xs, wsp, VOFF_, qkv, NW_, DM_);
        tabgen_kernel<<<S_ * DHH_ / 256, 256, 0, stream>>>(tab);
        // rope folded into k1k2 + selS (rotated q/k are pure intermediates)
        k1k2_kernel<true><<<B_ * KVH_ * M_, 64, 0, stream>>>(
            qkv, tab, k1, k2);
        selS_kernel<true><<<B_ * QH_ * 16, 64, 0, stream>>>(
            qkv, tab, k1, k2, meta);
        gatherV_kernel<1><<<B_ * QH_ * S_ / 4, 256, 0, stream>>>(
            qkv, meta, aob);
        dim3 g2(BS_ / 64, DM_ / 64);
        gemm_glds_kernel<1, 0><<<g2, 256, 0, stream>>>(
            aob, wob, 1 << 30, out, DM_, DM_);
    } else {
        float* aout = k2 + B_ * KVH_ * M_ * DHH_;
        float* meta = aout + (size_t)BS_ * DM_;
        dim3 g1(BS_ / 64, NW_ / 64);
        gemm_mfma_kernel<3, 2><<<g1, 256, 0, stream>>>(
            x, wq, wk, wv, KOFF_, VOFF_, qkv, NW_, DM_);
        rope_kernel<<<(BS_ * (QH_ + KVH_) * DHH_) / 256, 256, 0, stream>>>(qkv);
        k1k2_kernel<false><<<B_ * KVH_ * M_, 64, 0, stream>>>(
            qkv, nullptr, k1, k2);
        selS_kernel<false><<<B_ * QH_ * 16, 64, 0, stream>>>(
            qkv, nullptr, k1, k2, meta);
        gatherV_kernel<0><<<B_ * QH_ * S_ / 4, 256, 0, stream>>>(
            qkv, meta, aout);
        dim3 g2(BS_ / 64, DM_ / 64);
        gemm_mfma_kernel<1, 0><<<g2, 256, 0, stream>>>(
            aout, wo, wo, wo, 1 << 30, 1 << 30, out, DM_, DM_);
    }
}

// Round 18
// 98.103 us; speedup vs baseline: 1.0473x; 1.0473x over previous
//
#include <hip/hip_runtime.h>
#include <hip/hip_bf16.h>
#include <math.h>

// Problem constants (B=2, S=1024, DM=1024, QH=16, KVH=4)
constexpr int B_   = 2;
constexpr int S_   = 1024;
constexpr int DM_  = 1024;
constexpr int QH_  = 16;
constexpr int KVH_ = 4;
constexpr int DH_  = 64;
constexpr int DHH_ = 32;
constexpr int M_   = 32;    // sqrt(S)
constexpr int TOPK_ = 8;
constexpr int BS_  = B_ * S_;                    // 2048
constexpr int NW_  = QH_*DH_ + 2*KVH_*DH_;       // 1536 (q|k|v fused row)
constexpr int KOFF_ = QH_*DH_;                   // 1024
constexpr int VOFF_ = KOFF_ + KVH_*DH_;          // 1280

typedef __attribute__((ext_vector_type(8))) short short8v;   // 8 bf16 (4 VGPR)
typedef __attribute__((ext_vector_type(4))) short short4v;   // 4 bf16 (8B)
typedef __attribute__((ext_vector_type(4))) float float4v;   // MFMA acc

__device__ inline unsigned short bf16_rne(float f) {
    unsigned u = __float_as_uint(f);
    return (unsigned short)((u + 0x7FFFu + ((u >> 16) & 1u)) >> 16);
}
__device__ inline float bf16_back(unsigned short h) {
    return __uint_as_float(((unsigned)h) << 16);
}
__device__ __forceinline__ int swz(int srow) { return ((srow >> 1) & 3) << 4; }

// global -> LDS async copy, 16 B per lane at (ldsbase + lane*16).
__device__ __forceinline__ void gl_lds16(const void* g, void* l) {
    auto* gp = reinterpret_cast<const __attribute__((address_space(1))) unsigned int*>(
        reinterpret_cast<uintptr_t>(g));
    auto* lp = reinterpret_cast<__attribute__((address_space(3))) unsigned int*>(
        reinterpret_cast<uintptr_t>(l));
    __builtin_amdgcn_global_load_lds(gp, lp, 16, 0, 0);
}

// ---------------------------------------------------------------------------
// Sortable f64 keys (round-13 verified).
// ---------------------------------------------------------------------------
__device__ __forceinline__ unsigned sortable(float v) {
    unsigned u = __float_as_uint(v);
    return u ^ ((unsigned)(((int)u) >> 31) | 0x80000000u);
}
__device__ __forceinline__ float unsortable(unsigned s) {
    return __uint_as_float(s ^ (~((unsigned)(((int)s) >> 31)) | 0x80000000u));
}
__device__ __forceinline__ double mkkey(float v, int idx) {
    return (double)sortable(v) * 64.0 + (double)(63 - idx);
}
__device__ __forceinline__ void unkey(double kd, float& v, int& idx) {
    double t = trunc(kd * 0.015625);
    idx = 63 - (int)(kd - t * 64.0);
    v = unsortable((unsigned)t);
}
__device__ __forceinline__ double mkkey2(float v, int c, int row, int col) {
    return (double)sortable(v) * 65536.0 +
           (double)(65535 - (c * 1024 + row * 32 + col));
}
__device__ __forceinline__ void unkey2(double kd, float& v, int& vrow) {
    double t = trunc(kd * (1.0 / 65536.0));
    int low = 65535 - (int)(kd - t * 65536.0);
    v = unsortable((unsigned)t);
    vrow = ((low >> 5) & 31) * 32 + (low & 31);   // row*32 + col
}
__device__ __forceinline__ void ins8(double* l, double x) {
    l[7] = fmax(fmin(l[6], x), l[7]);
    l[6] = fmax(fmin(l[5], x), l[6]);
    l[5] = fmax(fmin(l[4], x), l[5]);
    l[4] = fmax(fmin(l[3], x), l[4]);
    l[3] = fmax(fmin(l[2], x), l[3]);
    l[2] = fmax(fmin(l[1], x), l[2]);
    l[1] = fmax(fmin(l[0], x), l[1]);
    l[0] = fmax(x, l[0]);
}

// ---------------------------------------------------------------------------
// Banded "LDS image" split planes (round-11 verified).
// ---------------------------------------------------------------------------
template<int L>
__device__ __forceinline__ void split_banded(const float* __restrict__ src,
                                             int i, char* __restrict__ dst,
                                             int row0)
{
    float4 v = reinterpret_cast<const float4*>(src)[i];
    int row = row0 + (i >> 8);
    int col = (i & 255) << 2;
    int srow = row & 63;
    char* band = dst + (size_t)(row >> 6) * (32u * L * 4096u);
    int off = ((col >> 5) * L) * 4096 + srow * 64 +
              ((((col & 31) >> 3) * 16) ^ swz(srow)) + (col & 7) * 2;
    float f[4] = {v.x, v.y, v.z, v.w};
#pragma unroll
    for (int l = 0; l < L; ++l) {
        short4v s;
#pragma unroll
        for (int e = 0; e < 4; ++e) {
            unsigned short h = bf16_rne(f[e]);
            s[e] = (short)h;
            f[e] -= bf16_back(h);
        }
        *reinterpret_cast<short4v*>(band + off + l * 4096) = s;
    }
}

__global__ __launch_bounds__(256) void split_all_kernel(
    const float* __restrict__ x,  const float* __restrict__ wq,
    const float* __restrict__ wk, const float* __restrict__ wv,
    const float* __restrict__ wo,
    char* __restrict__ xs, char* __restrict__ wsp, char* __restrict__ wob)
{
    constexpr int E0 = BS_ * DM_ / 4;
    constexpr int E1 = E0 + KOFF_ * DM_ / 4;
    constexpr int E2 = E1 + (VOFF_ - KOFF_) * DM_ / 4;
    constexpr int E3 = E2 + (NW_ - VOFF_) * DM_ / 4;
    constexpr int E4 = E3 + DM_ * DM_ / 4;
    int i = blockIdx.x * 256 + threadIdx.x;
    if (i < E0)      split_banded<3>(x,  i,      xs,  0);
    else if (i < E1) split_banded<3>(wq, i - E0, wsp, 0);
    else if (i < E2) split_banded<3>(wk, i - E1, wsp, KOFF_);
    else if (i < E3) split_banded<3>(wv, i - E2, wsp, VOFF_);
    else if (i < E4) split_banded<1>(wo, i - E3, wob, 0);
}

// ---------------------------------------------------------------------------
// global_load_lds MFMA GEMM, 64x64 tile (round-13/16 proven structure).
// ---------------------------------------------------------------------------
template<int LEVELS, int CROSS>
__global__ __launch_bounds__(256) void gemm_glds_kernel(
    const char* __restrict__ Aimg, const char* __restrict__ Bimg,
    int nVstart, float* __restrict__ C, int N, int K)
{
    __shared__ char As[2][LEVELS * 4096];
    __shared__ char Bs[2][LEVELS * 4096];
    const int tid = threadIdx.x;
    const int rowBase = blockIdx.x * 64;
    const int colBase = blockIdx.y * 64;
    const int lane = tid & 63, wvi = tid >> 6;
    const int wr = wvi >> 1, wc = wvi & 1;
    const int fr = lane & 15, fk = lane >> 4;
    const int LA = (colBase >= nVstart) ? 1 : LEVELS;

    const char* Ab = Aimg + (size_t)blockIdx.x * (32u * LEVELS * 4096u);
    const char* Bb = Bimg + (size_t)blockIdx.y * (32u * LEVELS * 4096u);

    float4v acc[2][2];
#pragma unroll
    for (int mi = 0; mi < 2; ++mi)
#pragma unroll
        for (int ni = 0; ni < 2; ++ni) acc[mi][ni] = (float4v)0.f;

    const int NKC = K >> 5;
    auto stage = [&](int kc, int buf) {
        const int kb = kc * LEVELS * 4096;
        const int toff = wvi * 1024 + lane * 16;
#pragma unroll
        for (int l = 0; l < LEVELS; ++l) if (l < LA) {
            gl_lds16(Ab + kb + l * 4096 + toff, &As[buf][l * 4096 + toff]);
            gl_lds16(Bb + kb + l * 4096 + toff, &Bs[buf][l * 4096 + toff]);
        }
    };

    stage(0, 0);
    __syncthreads();
    int buf = 0;
    for (int kc = 0; kc < NKC; ++kc) {
        if (kc + 1 < NKC) stage(kc + 1, buf ^ 1);
        short8v aF[LEVELS][2];
#pragma unroll
        for (int l = 0; l < LEVELS; ++l) if (l < LA)
#pragma unroll
            for (int mi = 0; mi < 2; ++mi) {
                int row = wr * 32 + mi * 16 + fr;
                aF[l][mi] = *reinterpret_cast<const short8v*>(
                    &As[buf][l * 4096 + row * 64 + ((fk * 16) ^ swz(row))]);
            }
#pragma unroll
        for (int lb = 0; lb < LEVELS; ++lb) {
            if (lb >= LA) continue;
            short8v bF[2];
#pragma unroll
            for (int ni = 0; ni < 2; ++ni) {
                int row = wc * 32 + ni * 16 + fr;
                bF[ni] = *reinterpret_cast<const short8v*>(
                    &Bs[buf][lb * 4096 + row * 64 + ((fk * 16) ^ swz(row))]);
            }
#pragma unroll
            for (int la = 0; la < LEVELS; ++la) {
                if (la >= LA || la + lb > CROSS) continue;
#pragma unroll
                for (int mi = 0; mi < 2; ++mi)
#pragma unroll
                    for (int ni = 0; ni < 2; ++ni)
                        acc[mi][ni] = __builtin_amdgcn_mfma_f32_16x16x32_bf16(
                            aF[la][mi], bF[ni], acc[mi][ni], 0, 0, 0);
            }
        }
        __syncthreads();
        buf ^= 1;
    }
#pragma unroll
    for (int mi = 0; mi < 2; ++mi)
#pragma unroll
        for (int ni = 0; ni < 2; ++ni) {
            int row0 = rowBase + wr * 32 + mi * 16 + fk * 4;
            int col  = colBase + wc * 32 + ni * 16 + fr;
#pragma unroll
            for (int j = 0; j < 4; ++j)
                C[(size_t)(row0 + j) * N + col] = acc[mi][ni][j];
        }
}

// ---------------------------------------------------------------------------
// Round-8 in-kernel-split GEMM — FALLBACK when ws_size too small.
// ---------------------------------------------------------------------------
template<int LEVELS, int CROSS>
__global__ __launch_bounds__(256) void gemm_mfma_kernel(
    const float* __restrict__ A,
    const float* __restrict__ W0, const float* __restrict__ W1,
    const float* __restrict__ W2, int n1, int n2,
    float* __restrict__ C, int N, int K)
{
    __shared__ short As[LEVELS * 64 * 32];
    __shared__ short Bs[LEVELS * 64 * 32];
    const int tid = threadIdx.x;
    const int rowBase = blockIdx.x * 64;
    const int colBase = blockIdx.y * 64;
    const int lane = tid & 63, wvi = tid >> 6;
    const int wr = wvi >> 1, wc = wvi & 1;
    const int fr = lane & 15, fk = lane >> 4;

    const float* aptr[2]; const float* bptr[2];
    int arow_[2], ac4_[2];
#pragma unroll
    for (int i = 0; i < 2; ++i) {
        int q = i * 256 + tid;
        int row = q >> 3, c4 = q & 7;
        arow_[i] = row; ac4_[i] = c4;
        aptr[i] = A + (size_t)(rowBase + row) * K + c4 * 4;
        int n = colBase + row;
        const float* wrow = (n < n1) ? W0 + (size_t)n * K
                          : (n < n2) ? W1 + (size_t)(n - n1) * K
                                     : W2 + (size_t)(n - n2) * K;
        bptr[i] = wrow + c4 * 4;
    }
    float4 pa[2], pb[2];
#pragma unroll
    for (int i = 0; i < 2; ++i) {
        pa[i] = *reinterpret_cast<const float4*>(aptr[i]);
        pb[i] = *reinterpret_cast<const float4*>(bptr[i]);
    }
    float4v acc[2][2];
#pragma unroll
    for (int mi = 0; mi < 2; ++mi)
#pragma unroll
        for (int ni = 0; ni < 2; ++ni) acc[mi][ni] = (float4v)0.f;

    const int NKC = K >> 5;
    for (int kc = 0; kc < NKC; ++kc) {
#pragma unroll
        for (int i = 0; i < 2; ++i) {
            int row = arow_[i];
            int base = row * 64 + ((ac4_[i] * 8) ^ swz(row));
            float fa[4] = {pa[i].x, pa[i].y, pa[i].z, pa[i].w};
            float fb[4] = {pb[i].x, pb[i].y, pb[i].z, pb[i].w};
#pragma unroll
            for (int l = 0; l < LEVELS; ++l) {
                short4v sa, sb;
#pragma unroll
                for (int e = 0; e < 4; ++e) {
                    unsigned short ha = bf16_rne(fa[e]);
                    unsigned short hb = bf16_rne(fb[e]);
                    sa[e] = (short)ha; sb[e] = (short)hb;
                    fa[e] -= bf16_back(ha);
                    fb[e] -= bf16_back(hb);
                }
                *reinterpret_cast<short4v*>((char*)As + l * 4096 + base) = sa;
                *reinterpret_cast<short4v*>((char*)Bs + l * 4096 + base) = sb;
            }
        }
        __syncthreads();
        if (kc + 1 < NKC) {
#pragma unroll
            for (int i = 0; i < 2; ++i) {
                pa[i] = *reinterpret_cast<const float4*>(aptr[i] + (kc+1)*32);
                pb[i] = *reinterpret_cast<const float4*>(bptr[i] + (kc+1)*32);
            }
        }
        short8v aF[LEVELS][2];
#pragma unroll
        for (int l = 0; l < LEVELS; ++l)
#pragma unroll
            for (int mi = 0; mi < 2; ++mi) {
                int row = wr * 32 + mi * 16 + fr;
                aF[l][mi] = *reinterpret_cast<const short8v*>(
                    (const char*)As + l * 4096 + row * 64 + ((fk * 16) ^ swz(row)));
            }
#pragma unroll
        for (int lb = 0; lb < LEVELS; ++lb) {
            short8v bF[2];
#pragma unroll
            for (int ni = 0; ni < 2; ++ni) {
                int row = wc * 32 + ni * 16 + fr;
                bF[ni] = *reinterpret_cast<const short8v*>(
                    (const char*)Bs + lb * 4096 + row * 64 + ((fk * 16) ^ swz(row)));
            }
#pragma unroll
            for (int la = 0; la < LEVELS; ++la) {
                if (la + lb > CROSS) continue;
#pragma unroll
                for (int mi = 0; mi < 2; ++mi)
#pragma unroll
                    for (int ni = 0; ni < 2; ++ni)
                        acc[mi][ni] = __builtin_amdgcn_mfma_f32_16x16x32_bf16(
                            aF[la][mi], bF[ni], acc[mi][ni], 0, 0, 0);
            }
        }
        __syncthreads();
    }
#pragma unroll
    for (int mi = 0; mi < 2; ++mi)
#pragma unroll
        for (int ni = 0; ni < 2; ++ni) {
            int row0 = rowBase + wr * 32 + mi * 16 + fk * 4;
            int col  = colBase + wc * 32 + ni * 16 + fr;
#pragma unroll
            for (int j = 0; j < 4; ++j)
                C[(size_t)(row0 + j) * N + col] = acc[mi][ni][j];
        }
}

// ---------------------------------------------------------------------------
// Trig table gen (round-16 verified): 32768 (s,d) pairs, bit-identical
// recipe (f64 pow -> f32 div -> f32 angle -> f64 sincos -> f32).
// ---------------------------------------------------------------------------
__global__ __launch_bounds__(256) void tabgen_kernel(float2* __restrict__ tab)
{
    int i = blockIdx.x * 256 + threadIdx.x;    // 32768
    int d = i & 31, s = i >> 5;
    double e = (double)d * (1.0 / 32.0);
    float pf = (float)pow(10000.0, e);         // == correctly-rounded powf
    float inv_freq = __fdiv_rn(1.0f, pf);      // numpy's 2nd f32 rounding
    float ang = __fmul_rn((float)s, inv_freq);
    double sn64, cs64;
    sincos((double)ang, &sn64, &cs64);
    tab[i] = make_float2((float)cs64, (float)sn64);
}

// rope via table: same cs/sn values, same strict-f32 rotation -> bit-identical.
__global__ __launch_bounds__(256) void rope_t_kernel(
    float* __restrict__ qkv, const float2* __restrict__ tab)
{
    int id = blockIdx.x * 256 + threadIdx.x;
    int d  = id & 31;
    int r  = id >> 5;
    int h  = r % (QH_ + KVH_);
    int bs = r / (QH_ + KVH_);
    int s  = bs & (S_ - 1);
    float* base = qkv + (size_t)bs * NW_ +
                  (h < QH_ ? h * DH_ : KOFF_ + (h - QH_) * DH_);
    float2 t = tab[(s << 5) | d];
    float x1 = base[d];
    float x2 = base[d + DHH_];
    base[d]        = __fadd_rn(__fmul_rn(x1, t.x), __fmul_rn(-x2, t.y));
    base[d + DHH_] = __fadd_rn(__fmul_rn(x2, t.x), __fmul_rn(x1, t.y));
}

// original self-contained rope (fallback path).
__global__ __launch_bounds__(256) void rope_kernel(float* __restrict__ qkv)
{
    int id = blockIdx.x * 256 + threadIdx.x;
    int d  = id & 31;
    int r  = id >> 5;
    int h  = r % (QH_ + KVH_);
    int bs = r / (QH_ + KVH_);
    int s  = bs & (S_ - 1);
    float* base = qkv + (size_t)bs * NW_ +
                  (h < QH_ ? h * DH_ : KOFF_ + (h - QH_) * DH_);
    double e = (double)d * (1.0 / 32.0);
    float pf = (float)pow(10000.0, e);
    float inv_freq = __fdiv_rn(1.0f, pf);
    float ang = __fmul_rn((float)s, inv_freq);
    double sn64, cs64;
    sincos((double)ang, &sn64, &cs64);
    float cs = (float)cs64;
    float sn = (float)sn64;
    float x1 = base[d];
    float x2 = base[d + DHH_];
    base[d]        = __fadd_rn(__fmul_rn(x1, cs), __fmul_rn(-x2, sn));
    base[d + DHH_] = __fadd_rn(__fmul_rn(x2, cs), __fmul_rn(x1, sn));
}

// ---------------------------------------------------------------------------
// k1/k2 grid sums: 256 blocks x 64 threads (round-16 verified).  Each output
// one thread's serial mc-ascending f64 sum -> bit-identical.
// ---------------------------------------------------------------------------
__global__ __launch_bounds__(64) void k1k2_kernel(
    const float* __restrict__ qkv, float* __restrict__ k1,
    float* __restrict__ k2)
{
    int blk = blockIdx.x;            // (b*KVH+kv)*32 + m : 256 blocks
    int m   = blk & 31;
    int bkv = blk >> 5;
    int b = bkv >> 2, kv = bkv & 3;
    int tid = threadIdx.x;
    int d = tid & 31;
    bool hi = tid >= 32;
    const float* kbase = qkv + (size_t)b * S_ * NW_ + KOFF_ + kv * DH_;
    double s = 0.;
    if (!hi) {
        for (int mc = 0; mc < M_; ++mc)
            s += (double)kbase[(size_t)(m * M_ + mc) * NW_ + d];
        k1[((b * KVH_ + kv) * M_ + m) * DHH_ + d] = (float)s;
    } else {
        for (int mc = 0; mc < M_; ++mc)
            s += (double)kbase[(size_t)(mc * M_ + m) * NW_ + DHH_ + d];
        k2[((b * KVH_ + kv) * M_ + m) * DHH_ + d] = (float)s;
    }
}

// ---------------------------------------------------------------------------
// selS: lane-per-problem selection (round-13 verified).
// ---------------------------------------------------------------------------
__global__ __launch_bounds__(64, 1) void selS_kernel(
    const float* __restrict__ qkv,
    const float* __restrict__ k1g, const float* __restrict__ k2g,
    float* __restrict__ meta)
{
    __shared__ __align__(16) float k1s[M_][DHH_];
    __shared__ __align__(16) float k2s[M_][DHH_];
    const int lane = threadIdx.x;
    const int bh   = blockIdx.x >> 4;
    const int sblk = blockIdx.x & 15;
    const int b    = bh >> 4;
    const int h    = bh & 15;
    const int kv   = h >> 2;
    const int s    = sblk * 64 + lane;

    const int kbase = (b * KVH_ + kv) * M_ * DHH_;
    for (int i = lane; i < M_ * DHH_; i += 64) {
        k1s[i >> 5][i & 31] = k1g[kbase + i];
        k2s[i >> 5][i & 31] = k2g[kbase + i];
    }
    __syncthreads();

    const float* qrow = qkv + (size_t)(b * S_ + s) * NW_ + h * DH_;

    double l1[8];
#pragma unroll
    for (int p = 0; p < 8; ++p) l1[p] = -1.0;
    {
        float q[32];
#pragma unroll
        for (int i = 0; i < 8; ++i)
            *reinterpret_cast<float4*>(&q[i * 4]) =
                *reinterpret_cast<const float4*>(qrow + i * 4);
        for (int m = 0; m < M_; ++m) {
            float acc = 0.f;
#pragma unroll
            for (int d4 = 0; d4 < 8; ++d4) {
                float4 k4 = *reinterpret_cast<const float4*>(&k1s[m][d4 * 4]);
                acc = fmaf(q[d4 * 4 + 0], k4.x, acc);
                acc = fmaf(q[d4 * 4 + 1], k4.y, acc);
                acc = fmaf(q[d4 * 4 + 2], k4.z, acc);
                acc = fmaf(q[d4 * 4 + 3], k4.w, acc);
            }
            ins8(l1, mkkey(acc, m));
        }
    }
    double l2[8];
#pragma unroll
    for (int p = 0; p < 8; ++p) l2[p] = -1.0;
    {
        float q[32];
#pragma unroll
        for (int i = 0; i < 8; ++i)
            *reinterpret_cast<float4*>(&q[i * 4]) =
                *reinterpret_cast<const float4*>(qrow + 32 + i * 4);
        for (int m = 0; m < M_; ++m) {
            float acc = 0.f;
#pragma unroll
            for (int d4 = 0; d4 < 8; ++d4) {
                float4 k4 = *reinterpret_cast<const float4*>(&k2s[m][d4 * 4]);
                acc = fmaf(q[d4 * 4 + 0], k4.x, acc);
                acc = fmaf(q[d4 * 4 + 1], k4.y, acc);
                acc = fmaf(q[d4 * 4 + 2], k4.z, acc);
                acc = fmaf(q[d4 * 4 + 3], k4.w, acc);
            }
            ins8(l2, mkkey(acc, m));
        }
    }
    float av[8], bv[8]; int i1v[8], i2v[8];
#pragma unroll
    for (int p = 0; p < 8; ++p) { unkey(l1[p], av[p], i1v[p]);
                                  unkey(l2[p], bv[p], i2v[p]); }

    double l[8];
#pragma unroll
    for (int p = 0; p < 8; ++p) l[p] = -1.0;
#define CAND(i, j) ins8(l, mkkey2(av[i] + bv[j], (i)*8+(j), i1v[i], i2v[j]))
    CAND(0,0); CAND(0,1); CAND(0,2); CAND(0,3);
    CAND(0,4); CAND(0,5); CAND(0,6); CAND(0,7);
    CAND(1,0); CAND(1,1); CAND(1,2); CAND(1,3);
    CAND(2,0); CAND(2,1); CAND(3,0); CAND(3,1);
    CAND(4,0); CAND(5,0); CAND(6,0); CAND(7,0);
#undef CAND
    float v2[8]; int vrow[8];
#pragma unroll
    for (int p = 0; p < 8; ++p) unkey2(l[p], v2[p], vrow[p]);

    float ex[8]; float sum = 0.f;
#pragma unroll
    for (int t = 0; t < 8; ++t) { ex[t] = expf((v2[t] - v2[0]) * 0.125f);
                                  sum += ex[t]; }
    const float inv = 1.0f / sum;

    float* mp = meta + ((size_t)(bh * S_ + s)) * 16;
#pragma unroll
    for (int t = 0; t < 8; ++t) {
        mp[t]     = ex[t] * inv;
        mp[8 + t] = __int_as_float(vrow[t]);
    }
}

// ---------------------------------------------------------------------------
// gatherV: one wave per problem, coalesced v-row gather (round-13 verified).
// ---------------------------------------------------------------------------
template<int OUTMODE>
__global__ __launch_bounds__(256) void gatherV_kernel(
    const float* __restrict__ qkv, const float* __restrict__ meta,
    void* __restrict__ aout)
{
    const int tid  = threadIdx.x;
    const int w    = tid >> 6, lane = tid & 63;
    const int pid  = blockIdx.x * 4 + w;       // (bh*S + s)
    const int bh   = pid >> 10;
    const int s    = pid & 1023;
    const int b    = bh >> 4;
    const int h    = bh & 15;
    const int kv   = h >> 2;

    const float* mp = meta + (size_t)pid * 16;
    float mv = (lane < 16) ? mp[lane] : 0.f;

    const float* vbase = qkv + (size_t)b * S_ * NW_ + VOFF_ + kv * DH_ + lane;
    float o = 0.f;
#pragma unroll
    for (int t = 0; t < 8; ++t) {
        float wt = __shfl(mv, t);
        int   vr = __float_as_int(__shfl(mv, 8 + t));
        o = fmaf(wt, vbase[(size_t)vr * NW_], o);
    }
    int orow = b * S_ + s;
    int ocol = h * DH_ + lane;
    if (OUTMODE == 1) {
        int srow = orow & 63;
        size_t byteoff = (size_t)(orow >> 6) * (32u * 4096u)
                       + (size_t)(ocol >> 5) * 4096 + srow * 64
                       + ((((ocol & 31) >> 3) * 16) ^ swz(srow))
                       + (ocol & 7) * 2;
        *reinterpret_cast<short*>((char*)aout + byteoff) = (short)bf16_rne(o);
    } else {
        ((float*)aout)[(size_t)orow * (QH_ * DH_) + ocol] = o;
    }
}

// ---------------------------------------------------------------------------
extern "C" void kernel_launch(void* const* d_in, const int* in_sizes, int n_in,
                              void* d_out, int out_size, void* d_ws,
                              size_t ws_size, hipStream_t stream)
{
    const float* x  = (const float*)d_in[0];
    const float* wq = (const float*)d_in[1];
    const float* wk = (const float*)d_in[2];
    const float* wv = (const float*)d_in[3];
    const float* wo = (const float*)d_in[4];
    float* out = (float*)d_out;

    float* wsf = (float*)d_ws;
    float* qkv = wsf;                                    // 2048*1536 f32
    float* k1  = qkv + (size_t)BS_ * NW_;                // 8192 f32
    float* k2  = k1 + B_ * KVH_ * M_ * DHH_;             // 8192 f32

    const bool fast = ws_size >= 40960000ull;

    if (fast) {
        char* xs  = (char*)(k2 + B_ * KVH_ * M_ * DHH_);
        char* wsp = xs  + (size_t)3 * BS_ * DM_ * 2;
        char* wob = wsp + (size_t)3 * NW_ * DM_ * 2;
        char* aob = wob + (size_t)DM_ * DM_ * 2;
        float*  meta = (float*)xs;              // xs dead after qkv GEMM (2MB)
        float2* tab  = (float2*)(xs + (4u << 20));  // +4MB: 256KB trig table

        constexpr int NSLOT = (BS_*DM_ + KOFF_*DM_ + (VOFF_-KOFF_)*DM_ +
                               (NW_-VOFF_)*DM_ + DM_*DM_) / 4;
        split_all_kernel<<<(NSLOT + 255) / 256, 256, 0, stream>>>(
            x, wq, wk, wv, wo, xs, wsp, wob);

        dim3 g1(BS_ / 64, NW_ / 64);
        gemm_glds_kernel<3, 2><<<g1, 256, 0, stream>>>(
            xs, wsp, VOFF_, qkv, NW_, DM_);
        tabgen_kernel<<<S_ * DHH_ / 256, 256, 0, stream>>>(tab);
        rope_t_kernel<<<(BS_ * (QH_ + KVH_) * DHH_) / 256, 256, 0, stream>>>(
            qkv, tab);
        k1k2_kernel<<<B_ * KVH_ * M_, 64, 0, stream>>>(qkv, k1, k2);
        selS_kernel<<<B_ * QH_ * 16, 64, 0, stream>>>(qkv, k1, k2, meta);
        gatherV_kernel<1><<<B_ * QH_ * S_ / 4, 256, 0, stream>>>(
            qkv, meta, aob);
        dim3 g2(BS_ / 64, DM_ / 64);
        gemm_glds_kernel<1, 0><<<g2, 256, 0, stream>>>(
            aob, wob, 1 << 30, out, DM_, DM_);
    } else {
        float* aout = k2 + B_ * KVH_ * M_ * DHH_;
        float* meta = aout + (size_t)BS_ * DM_;
        dim3 g1(BS_ / 64, NW_ / 64);
        gemm_mfma_kernel<3, 2><<<g1, 256, 0, stream>>>(
            x, wq, wk, wv, KOFF_, VOFF_, qkv, NW_, DM_);
        rope_kernel<<<(BS_ * (QH_ + KVH_) * DHH_) / 256, 256, 0, stream>>>(qkv);
        k1k2_kernel<<<B_ * KVH_ * M_, 64, 0, stream>>>(qkv, k1, k2);
        selS_kernel<<<B_ * QH_ * 16, 64, 0, stream>>>(qkv, k1, k2, meta);
        gatherV_kernel<0><<<B_ * QH_ * S_ / 4, 256, 0, stream>>>(
            qkv, meta, aout);
        dim3 g2(BS_ / 64, DM_ / 64);
        gemm_mfma_kernel<1, 0><<<g2, 256, 0, stream>>>(
            aout, wo, wo, wo, 1 << 30, 1 << 30, out, DM_, DM_);
    }
}